// Round 9
// baseline (2552.212 us; speedup 1.0000x reference)
//
#include <hip/hip_runtime.h>

// LSTM B=1024 T=512 H=256 (input_size=1, output_size=1) on MI355X.
// R9: all 256 CUs via batch-split (4 rows/block) + intra-wave gate
// redistribution. R8 analysis: per-active-CU VALU 58% (transcendentals) +
// MFMA 24% -> issue-bound on 64 CUs. Batch-split alone doesn't cut wave-level
// trans (real C rows land only in quad0 lanes); so after the MFMAs quad0
// writes its 32 real acc floats to a per-wave LDS xchg (8 ds_write_b128) and
// all 64 lanes read back 2 elements each (8 ds_read_b32, intra-wave, no
// barrier) -> trans/wave 80->20, gate VALU /4. Per-CU MFMA unchanged (C-tile
// 3/4 duplicate rows -- M=16 is the min shape).
// Step-loop idioms reverted to R4's proven set: __syncthreads, padded hbuf
// (stride 272: 136 dw = 8 mod 32 -> 2-way max on A-frag reads), whole-tile
// o-stream prefetch issued ~half-step before use. (R6/R8's asm barrier +
// swizzle + reorder carried an undiagnosed ~250us cost -- dropped.)
// Per wave w: i,f tiles (4) reg/AGPR-resident; g tiles (2) in LDS (128 KB);
// o tiles (2) streamed from L2 through one rotating 32-reg buffer.

#define HID 256
#define TT 512
#define NBLK 256
#define THREADS 512
#define HP 272           // hbuf row stride (bf16 elems)

typedef float v4f __attribute__((ext_vector_type(4)));
typedef unsigned int v4u __attribute__((ext_vector_type(4)));
typedef __bf16 v8bf __attribute__((ext_vector_type(8)));

__device__ __forceinline__ unsigned short f2bf(float f) {
    unsigned int u = __builtin_bit_cast(unsigned int, f);
    u += 0x7fffu + ((u >> 16) & 1u);   // RNE
    return (unsigned short)(u >> 16);
}
__device__ __forceinline__ float bf2f(unsigned short s) {
    unsigned int u = ((unsigned int)s) << 16;
    return __builtin_bit_cast(float, u);
}
__device__ __forceinline__ float fsigmoid(float x) {
    float e = exp2f(x * -1.44269504f);
    return __builtin_amdgcn_rcpf(1.0f + e);
}
__device__ __forceinline__ float ftanh(float x) {
    float e = exp2f(x * 2.88539008f);
    return 1.0f - 2.0f * __builtin_amdgcn_rcpf(1.0f + e);
}

// W_hh fp32 [1024][256] -> bf16 fragment order:
// Wbf[((Tn*8+kc)*64+lane)*8 + j] = bf16(W_hh[16*Tn+(lane&15)][32*kc+(lane>>4)*8+j])
__global__ void wconv_kernel(const float* __restrict__ Whh,
                             unsigned short* __restrict__ Wbf) {
    int tid = blockIdx.x * blockDim.x + threadIdx.x;   // 0..32767
    int lane = tid & 63;
    int frag = tid >> 6;
    int Tn = frag >> 3;
    int kc = frag & 7;
    int n  = Tn * 16 + (lane & 15);
    int kb = kc * 32 + (lane >> 4) * 8;
    const float* src = Whh + (size_t)n * HID + kb;
    unsigned short* dst = Wbf + (size_t)tid * 8;
#pragma unroll
    for (int j = 0; j < 8; ++j) dst[j] = f2bf(src[j]);
}

#define MFMA8(ACC, BARR, BOFF)                                               \
    _Pragma("unroll")                                                        \
    for (int kc = 0; kc < 8; ++kc)                                           \
        ACC = __builtin_amdgcn_mfma_f32_16x16x32_bf16(afrag[kc],             \
                  BARR[(BOFF) + kc], ACC, 0, 0, 0);

#define LDSTILE(ACC, SLOT)                                                   \
    { v8bf bl_[8];                                                           \
      _Pragma("unroll")                                                      \
      for (int kc = 0; kc < 8; ++kc)                                         \
          bl_[kc] = __builtin_bit_cast(v8bf, *(const v4u*)(Wlds +            \
                      ((size_t)(((SLOT) * 8 + kc) * 64 + lane)) * 8));       \
      MFMA8(ACC, bl_, 0) }

#define SLOADT(SB, TN)                                                       \
    _Pragma("unroll")                                                        \
    for (int kc = 0; kc < 8; ++kc)                                           \
        SB[kc] = __builtin_bit_cast(v8bf,                                    \
                   Wv[((size_t)(TN) * 8 + kc) * 64 + lane]);

__global__ __launch_bounds__(THREADS, 2)
void lstm_kernel(const float* __restrict__ x,
                 const float* __restrict__ W_ih,
                 const float* __restrict__ b_ih,
                 const float* __restrict__ b_hh,
                 const float* __restrict__ W_lin,
                 const float* __restrict__ b_lin,
                 const unsigned short* __restrict__ Wbf,
                 float* __restrict__ out) {
    __shared__ __align__(16) unsigned short Wlds[16 * 8 * 64 * 8]; // 128 KB g-tiles
    __shared__ __align__(16) unsigned short hbuf[2][4 * HP];       // 4.25 KB
    __shared__ __align__(16) float xchg[8][2][4][16][4];           // 16 KB [w][S][G][l4][r]
    __shared__ float part[THREADS];                                // 2 KB
    __shared__ float p2[64];

    const int tid  = threadIdx.x;
    const int lane = tid & 63;
    const int w    = tid >> 6;      // wave 0..7
    const int l4   = lane & 15;
    const int quad = lane >> 4;
    const int r0   = blockIdx.x * 4;   // 4 batch rows per block

    const v4u* __restrict__ Wv = (const v4u*)Wbf;

    // Per-lane gate constants: unit u(S) = 16*(w+8S)+l4, gates G=0..3 (i,f,g,o)
    float wi[8], bb[8];
#pragma unroll
    for (int S = 0; S < 2; ++S) {
        int u = 16 * (w + 8 * S) + l4;
#pragma unroll
        for (int G = 0; G < 4; ++G) {
            wi[S * 4 + G] = W_ih[G * 256 + u];
            bb[S * 4 + G] = b_ih[G * 256 + u] + b_hh[G * 256 + u];
        }
    }

    // reg/AGPR-resident i,f tiles: [0]=i,S0(Tn=w) [1]=f,S0(16+w) [2]=i,S1(8+w) [3]=f,S1(24+w)
    v8bf wres[32];
    {
        const int tns[4] = {w, 16 + w, 8 + w, 24 + w};
#pragma unroll
        for (int qq = 0; qq < 4; ++qq)
#pragma unroll
            for (int kc = 0; kc < 8; ++kc)
                wres[qq * 8 + kc] = __builtin_bit_cast(v8bf,
                    Wv[((size_t)(tns[qq]) * 8 + kc) * 64 + lane]);
    }
    // LDS-resident g-tiles: slot w*2+S <- Tn = 32 + w + 8*S
#pragma unroll
    for (int S = 0; S < 2; ++S) {
        int Tn = 32 + w + 8 * S;
        int slot = w * 2 + S;
#pragma unroll
        for (int kc = 0; kc < 8; ++kc) {
            v4u d = Wv[((size_t)Tn * 8 + kc) * 64 + lane];
            *(v4u*)(Wlds + ((size_t)((slot * 8 + kc) * 64 + lane)) * 8) = d;
        }
    }
    // h(0) = 0
    for (int i = tid; i < 4 * HP; i += THREADS) {
        hbuf[0][i] = 0;
        hbuf[1][i] = 0;
    }
    __syncthreads();

    // streamed o-tiles through one rotating buffer; prologue: o,S0 (Tn=48+w)
    v8bf sb[8];
    SLOADT(sb, 48 + w)

    float cst[2] = {0.0f, 0.0f};   // c for (row=quad, unit u(S))

    // x is wave-uniform: rows r0..r0+3
    float xv[4];
#pragma unroll
    for (int r = 0; r < 4; ++r) xv[r] = x[(size_t)(r0 + r) * TT];

    for (int t = 0; t < TT; ++t) {
        const unsigned short* hb = hbuf[t & 1];
        unsigned short* hn = hbuf[(t & 1) ^ 1];

        // A-frags: row (l4&3) real h rows; rows 4-15 duplicate (outputs unused)
        v8bf afrag[8];
        const unsigned short* hrow = hb + (l4 & 3) * HP + quad * 8;
#pragma unroll
        for (int kc = 0; kc < 8; ++kc)
            afrag[kc] = __builtin_bit_cast(v8bf, *(const v4u*)(hrow + kc * 32));

        // ---- S=0: MFMAs, then quad0 parks real rows in xchg ----
        {
            v4f ai, af2, ag, ao;
#pragma unroll
            for (int r = 0; r < 4; ++r) {
                ai[r]  = xv[r] * wi[0] + bb[0];
                af2[r] = xv[r] * wi[1] + bb[1];
                ag[r]  = xv[r] * wi[2] + bb[2];
                ao[r]  = xv[r] * wi[3] + bb[3];
            }
            MFMA8(ao, sb, 0)                // o,S0 (prefetched)
            SLOADT(sb, 56 + w)              // o,S1: consumed ~half-step later
            MFMA8(ai, wres, 0)              // i,S0
            MFMA8(af2, wres, 8)             // f,S0
            LDSTILE(ag, w * 2 + 0)          // g,S0
            if (quad == 0) {
                *(v4f*)&xchg[w][0][0][l4][0] = ai;
                *(v4f*)&xchg[w][0][1][l4][0] = af2;
                *(v4f*)&xchg[w][0][2][l4][0] = ag;
                *(v4f*)&xchg[w][0][3][l4][0] = ao;
            }
        }
        // ---- S=1 ----
        {
            v4f ai, af2, ag, ao;
#pragma unroll
            for (int r = 0; r < 4; ++r) {
                ai[r]  = xv[r] * wi[4] + bb[4];
                af2[r] = xv[r] * wi[5] + bb[5];
                ag[r]  = xv[r] * wi[6] + bb[6];
                ao[r]  = xv[r] * wi[7] + bb[7];
            }
            // x prefetch for t+1 (xv dead after init above)
            {
                int tn = (t + 1 < TT) ? (t + 1) : t;
#pragma unroll
                for (int r = 0; r < 4; ++r)
                    xv[r] = x[(size_t)(r0 + r) * TT + tn];
            }
            MFMA8(ao, sb, 0)                // o,S1
            SLOADT(sb, 48 + w)              // o,S0 for t+1
            MFMA8(ai, wres, 16)             // i,S1
            MFMA8(af2, wres, 24)            // f,S1
            LDSTILE(ag, w * 2 + 1)          // g,S1
            if (quad == 0) {
                *(v4f*)&xchg[w][1][0][l4][0] = ai;
                *(v4f*)&xchg[w][1][1][l4][0] = af2;
                *(v4f*)&xchg[w][1][2][l4][0] = ag;
                *(v4f*)&xchg[w][1][3][l4][0] = ao;
            }
        }

        // ---- redistributed gates: lane owns (row=quad, unit u(S)), S=0,1 ----
        // (intra-wave DS dependency; compiler inserts lgkmcnt wait)
#pragma unroll
        for (int S = 0; S < 2; ++S) {
            float gi = fsigmoid(xchg[w][S][0][l4][quad]);
            float gf = fsigmoid(xchg[w][S][1][l4][quad]);
            float gg = ftanh   (xchg[w][S][2][l4][quad]);
            float go = fsigmoid(xchg[w][S][3][l4][quad]);
            float cn = gf * cst[S] + gi * gg;
            cst[S] = cn;
            hn[quad * HP + 16 * (w + 8 * S) + l4] = f2bf(go * ftanh(cn));
        }

        __syncthreads();
    }

    // Epilogue: final h in hbuf[0]. out[r0+b] = h[b].W_lin + b_lin
    {
        int row = tid >> 7, j0 = (tid & 127) * 2;
        float p = bf2f(hbuf[0][row * HP + j0]) * W_lin[j0]
                + bf2f(hbuf[0][row * HP + j0 + 1]) * W_lin[j0 + 1];
        part[tid] = p;
    }
    __syncthreads();
    if (tid < 64) {
        float s = 0.0f;
#pragma unroll
        for (int k = 0; k < 8; ++k) s += part[tid * 8 + k];
        p2[tid] = s;
    }
    __syncthreads();
    if (tid < 4) {
        float s = 0.0f;
#pragma unroll
        for (int k = 0; k < 16; ++k) s += p2[tid * 16 + k];
        out[r0 + tid] = s + b_lin[0];
    }
}

extern "C" void kernel_launch(void* const* d_in, const int* in_sizes, int n_in,
                              void* d_out, int out_size, void* d_ws, size_t ws_size,
                              hipStream_t stream) {
    const float* x     = (const float*)d_in[0];
    const float* W_ih  = (const float*)d_in[1];
    const float* W_hh  = (const float*)d_in[2];
    const float* b_ih  = (const float*)d_in[3];
    const float* b_hh  = (const float*)d_in[4];
    const float* W_lin = (const float*)d_in[5];
    const float* b_lin = (const float*)d_in[6];
    unsigned short* Wbf = (unsigned short*)d_ws;   // 512 KB

    wconv_kernel<<<128, 256, 0, stream>>>(W_hh, Wbf);
    lstm_kernel<<<NBLK, THREADS, 0, stream>>>(x, W_ih, b_ih, b_hh, W_lin, b_lin,
                                              Wbf, (float*)d_out);
}